// Round 10
// baseline (629.267 us; speedup 1.0000x reference)
//
#include <hip/hip_runtime.h>
#include <hip/hip_fp16.h>

// Problem constants: B=16, N=128, H=128, BD=64, P=256
using f16x4 = __attribute__((ext_vector_type(4))) _Float16;
using f16x8 = __attribute__((ext_vector_type(8))) _Float16;
using f32x4 = __attribute__((ext_vector_type(4))) float;

__device__ __forceinline__ f16x4 ld_f16x4(const void* p) {
    return *reinterpret_cast<const f16x4*>(p);
}
__device__ __forceinline__ f16x8 ld_f16x8(const void* p) {
    return *reinterpret_cast<const f16x8*>(p);
}

// ---------------------------------------------------------------------------
// k-slot convention (consistent across BOTH MFMA operands => contraction is
// exact for any bijection): for K=32 f16 MFMA, lane group lk (lane>>4),
// register element e (0..7) holds k-slot (lk, e).
//  GEMM1 labeling: k = s32*32 + lk*8 + e          (plain, W2bt = plain transpose)
//  GEMM2 labeling: k = ks*32 + sigma(lk,e), sigma = (e>>2)*16 + 4*lk + (e&3)
//   (matches GEMM1's C/D quad packing of u, so u needs NO shuffles).
//
// Prep kernel A: W2bt[p][k] = W2[128+k][p] (f16 plain transpose, 64/row).
//  W3 -> W3s: [ks][row p'][4 slots x 8 f16]; slot s at row holds k-group
//  g = s ^ ((row>>1)&3) (read-side bank swizzle folded in), element e ->
//  k = ks*32 + sigma(g,e).
// ---------------------------------------------------------------------------
__global__ void sp_wconv(const float* __restrict__ W2, const float* __restrict__ W3,
                         _Float16* __restrict__ W2bt, _Float16* __restrict__ W3s) {
    int t = blockIdx.x * 256 + threadIdx.x;   // grid covers 65536
    if (t < 16384) {
        int p = t >> 6, k = t & 63;
        W2bt[t] = (_Float16)W2[(128 + k) * 256 + p];
    }
    {
        int ks = t >> 13, rem = t & 8191;
        int row = rem >> 5, inner = rem & 31;
        int slot = inner >> 3, e = inner & 7;
        int g = slot ^ ((row >> 1) & 3);
        int k = ks * 32 + ((e & 4) << 2) + (g << 2) + (e & 3);
        W3s[t] = (_Float16)W3[k * 256 + row];
    }
}

// ---------------------------------------------------------------------------
// Prep kernel B: hp16[b*128+j][p] = hid[b,j,:] @ W2[0:128,p] + b2[p]  (f16)
// ---------------------------------------------------------------------------
__global__ void sp_hpart(const float* __restrict__ hs, const float* __restrict__ W2,
                         const float* __restrict__ b2, _Float16* __restrict__ hp16) {
    __shared__ float sh[8 * 128];
    int rb = blockIdx.x * 8;
    int tid = threadIdx.x;
    for (int t = tid; t < 1024; t += 256) sh[t] = hs[rb * 128 + t];
    __syncthreads();
    float acc[8];
    float bb = b2[tid];
#pragma unroll
    for (int r = 0; r < 8; ++r) acc[r] = bb;
    for (int k = 0; k < 128; ++k) {
        float w = W2[k * 256 + tid];
#pragma unroll
        for (int r = 0; r < 8; ++r) acc[r] += sh[r * 128 + k] * w;
    }
#pragma unroll
    for (int r = 0; r < 8; ++r) hp16[(rb + r) * 256 + tid] = (_Float16)acc[r];
}

// ---------------------------------------------------------------------------
// Main kernel: one block per (b, ph, i-group of 8) -> grid 512 (2/CU, fully
// resident). 4 waves; wave wj owns j in [32wj, 32wj+32).
//  Stage W3 half (64KB) to LDS ONCE (1 barrier). Then 8 i-iterations with
//  ZERO barriers: sW3 read-only; each wave writes only its private sPoolH
//  slice. Waves drift across phases -> VALU/LDS/MFMA co-schedule (m114).
//  Per i: enc -> GEMM1 (K=32, transposed) -> u in regs -> GEMM2 (K=32) from
//  resident LDS -> per-wave masked max -> sPoolH[wj][ii][...] (f16).
//  Block end: 1 barrier, 4-wave max + b3 -> pooled rows (d_out, write-only).
// LDS: 64KB W3 + 8KB pool = 72KB -> 2 blocks/CU. Regs ~170 -> (256,2).
// ---------------------------------------------------------------------------
__global__ __launch_bounds__(256, 2) void sp_main(
    const float* __restrict__ pos, const float* __restrict__ W1,
    const float* __restrict__ b1, const float* __restrict__ b3,
    const _Float16* __restrict__ hp16, const _Float16* __restrict__ W2bt,
    const _Float16* __restrict__ W3s, float* __restrict__ pool) {
    __shared__ __align__(16) char sW3[8][8192];    // [ks][row' 128][64B]
    __shared__ _Float16 sPoolH[4][8][128];         // [wj][ii][p'-local]

    const int bid = blockIdx.x;
    const int ig = bid & 15, ph = (bid >> 4) & 1, b = bid >> 5;
    const int tid = threadIdx.x;
    const int wj = tid >> 6, lane = tid & 63;
    const int l15 = lane & 15, lk = lane >> 4;

    // --- stage W3 half (64KB) once; linear conflict-free writes ------------
    {
        const uint4* W3v = (const uint4*)W3s + ph * 512;
        uint4* dst = (uint4*)sW3;
#pragma unroll
        for (int c = 0; c < 16; ++c) {
            dst[c * 256 + tid] = W3v[c * 256 + tid + (c >> 1) * 512];
        }
    }

    // --- i-invariant fragments ---------------------------------------------
    f32x4 x0[2], x1[2], y0[2], y1[2], c0[2], c1[2];
#pragma unroll
    for (int s32 = 0; s32 < 2; ++s32) {
        int k0 = s32 * 32 + lk * 8;
        x0[s32] = *(const f32x4*)(W1 + k0);      x1[s32] = *(const f32x4*)(W1 + k0 + 4);
        y0[s32] = *(const f32x4*)(W1 + 64 + k0); y1[s32] = *(const f32x4*)(W1 + 64 + k0 + 4);
        c0[s32] = *(const f32x4*)(b1 + k0);      c1[s32] = *(const f32x4*)(b1 + k0 + 4);
    }
    float pjx[2], pjy[2];
#pragma unroll
    for (int jt = 0; jt < 2; ++jt) {
        int j = wj * 32 + jt * 16 + l15;
        pjx[jt] = pos[(b * 128 + j) * 2 + 0];
        pjy[jt] = pos[(b * 128 + j) * 2 + 1];
    }
    const _Float16* hpb = hp16 + (b * 128 + wj * 32 + l15) * 256 + lk * 4;
    const int slot = lk ^ ((l15 >> 1) & 3);   // read-side bank swizzle

    __syncthreads();   // sW3 ready

    // ======================= barrier-free i-loop ===========================
#pragma unroll 1
    for (int ii = 0; ii < 8; ++ii) {
        const int i = ig * 8 + ii;
        const float pix = pos[(b * 128 + i) * 2 + 0];
        const float piy = pos[(b * 128 + i) * 2 + 1];

        // --- enc as K=32 B-fragments: k = s32*32 + lk*8 + e ----------------
        f16x8 benc[2][2];
#pragma unroll
        for (int s32 = 0; s32 < 2; ++s32) {
#pragma unroll
            for (int jt = 0; jt < 2; ++jt) {
                float rx = pjx[jt] - pix, ry = pjy[jt] - piy;
                f16x8 v;
#pragma unroll
                for (int e = 0; e < 4; ++e) {
                    float t0 = fmaf(rx, x0[s32][e], fmaf(ry, y0[s32][e], c0[s32][e]));
                    float t1 = fmaf(rx, x1[s32][e], fmaf(ry, y1[s32][e], c1[s32][e]));
                    v[e]     = (_Float16)(t0 > 0.f ? t0 : 0.f);
                    v[e + 4] = (_Float16)(t1 > 0.f ? t1 : 0.f);
                }
                benc[jt][s32] = v;
            }
        }

        // --- GEMM1 (transposed, K=32) + pack u = GEMM2 A-frags -------------
        // D: p = pt*16 + 4lk + r, j = wj*32 + jt*16 + l15
        f16x8 u[2][8];
#pragma unroll
        for (int pt = 0; pt < 16; ++pt) {
            f32x4 a0 = (f32x4){0.f, 0.f, 0.f, 0.f};
            f32x4 a1 = (f32x4){0.f, 0.f, 0.f, 0.f};
#pragma unroll
            for (int s32 = 0; s32 < 2; ++s32) {
                f16x8 aw = ld_f16x8(W2bt + (pt * 16 + l15) * 64 + s32 * 32 + lk * 8);
                a0 = __builtin_amdgcn_mfma_f32_16x16x32_f16(aw, benc[0][s32], a0, 0, 0, 0);
                a1 = __builtin_amdgcn_mfma_f32_16x16x32_f16(aw, benc[1][s32], a1, 0, 0, 0);
            }
            f16x4 h0 = ld_f16x4(hpb + pt * 16);
            f16x4 h1 = ld_f16x4(hpb + 16 * 256 + pt * 16);
            const int ks = pt >> 1, half = (pt & 1) * 4;
#pragma unroll
            for (int r = 0; r < 4; ++r) {
                float t0 = a0[r] + (float)h0[r];
                float t1 = a1[r] + (float)h1[r];
                u[0][ks][half + r] = (_Float16)(t0 > 0.f ? t0 : 0.f);
                u[1][ks][half + r] = (_Float16)(t1 > 0.f ? t1 : 0.f);
            }
        }

        // --- GEMM2 (K=32) from resident LDS, no barriers --------------------
        f32x4 eacc[2][8];
#pragma unroll
        for (int jt = 0; jt < 2; ++jt)
#pragma unroll
            for (int pt = 0; pt < 8; ++pt) eacc[jt][pt] = (f32x4){0.f, 0.f, 0.f, 0.f};

#pragma unroll
        for (int ks = 0; ks < 8; ++ks) {
#pragma unroll
            for (int pt = 0; pt < 8; ++pt) {
                f16x8 bf = ld_f16x8(sW3[ks] + (pt * 16 + l15) * 64 + slot * 16);
                eacc[0][pt] = __builtin_amdgcn_mfma_f32_16x16x32_f16(u[0][ks], bf, eacc[0][pt], 0, 0, 0);
                eacc[1][pt] = __builtin_amdgcn_mfma_f32_16x16x32_f16(u[1][ks], bf, eacc[1][pt], 0, 0, 0);
            }
        }

        // --- masked max over this wave's 32 j -> private sPoolH slice ------
        // eacc: row j = wj*32 + jt*16 + 4lk + r, col p' = ph*128 + pt*16 + l15
#pragma unroll
        for (int pt = 0; pt < 8; ++pt) {
            float m = -INFINITY;
#pragma unroll
            for (int jt = 0; jt < 2; ++jt) {
#pragma unroll
                for (int r = 0; r < 4; ++r) {
                    int row = wj * 32 + jt * 16 + lk * 4 + r;
                    float v = eacc[jt][pt][r];
                    if (row != i) m = fmaxf(m, v);
                }
            }
            m = fmaxf(m, __shfl_xor(m, 16));
            m = fmaxf(m, __shfl_xor(m, 32));
            if (lane < 16) sPoolH[wj][ii][pt * 16 + l15] = (_Float16)m;
        }
    }
    __syncthreads();   // all waves' sPoolH complete

    // --- cross-wave max + b3 -> pooled rows (d_out, write-only) ------------
#pragma unroll
    for (int q = 0; q < 4; ++q) {
        int idx = q * 256 + tid;           // 0..1023 = 8 ii x 128 p'-local
        int ii = idx >> 7, t = idx & 127;
        float v = fmaxf(fmaxf((float)sPoolH[0][ii][t], (float)sPoolH[1][ii][t]),
                        fmaxf((float)sPoolH[2][ii][t], (float)sPoolH[3][ii][t]));
        int p = ph * 128 + t;
        pool[(b * 128 + ig * 8 + ii) * 256 + p] = v + b3[p];
    }
}

// ---------------------------------------------------------------------------
// Final: io = io @ Wout + bout, IN PLACE on d_out (8 rows per block; rows
// staged to LDS behind a barrier before any write -> in-place safe).
// ---------------------------------------------------------------------------
__global__ void sp_out(const float* __restrict__ Wout, const float* __restrict__ bout,
                       float* __restrict__ io) {
    __shared__ float sp[8 * 256];
    int rb = blockIdx.x * 8;
    int tid = threadIdx.x;
    for (int t = tid; t < 2048; t += 256) sp[t] = io[rb * 256 + t];
    __syncthreads();
    float acc[8];
    float bb = bout[tid];
#pragma unroll
    for (int r = 0; r < 8; ++r) acc[r] = bb;
    for (int k = 0; k < 256; ++k) {
        float w = Wout[k * 256 + tid];
#pragma unroll
        for (int r = 0; r < 8; ++r) acc[r] += sp[r * 256 + k] * w;
    }
#pragma unroll
    for (int r = 0; r < 8; ++r) io[(rb + r) * 256 + tid] = acc[r];
}

extern "C" void kernel_launch(void* const* d_in, const int* in_sizes, int n_in,
                              void* d_out, int out_size, void* d_ws, size_t ws_size,
                              hipStream_t stream) {
    const float* hs   = (const float*)d_in[0];
    const float* pos  = (const float*)d_in[1];
    const float* W1   = (const float*)d_in[2];
    const float* b1   = (const float*)d_in[3];
    const float* W2   = (const float*)d_in[4];
    const float* b2   = (const float*)d_in[5];
    const float* W3   = (const float*)d_in[6];
    const float* b3   = (const float*)d_in[7];
    const float* Wout = (const float*)d_in[8];
    const float* bout = (const float*)d_in[9];
    float* out = (float*)d_out;

    // ws layout: hp16 1MB | W2bt 32KB | W3s 128KB  (~1.2MB total)
    _Float16* hp16 = (_Float16*)d_ws;
    _Float16* W2bt = (_Float16*)((char*)d_ws + (1 << 20));
    _Float16* W3s  = (_Float16*)((char*)d_ws + (1 << 20) + 32768);

    sp_wconv<<<256, 256, 0, stream>>>(W2, W3, W2bt, W3s);
    sp_hpart<<<256, 256, 0, stream>>>(hs, W2, b2, hp16);
    sp_main<<<512, 256, 0, stream>>>(pos, W1, b1, b3, hp16, W2bt, W3s, out);
    sp_out<<<256, 256, 0, stream>>>(Wout, bout, out);
}

// Round 11
// 221.613 us; speedup vs baseline: 2.8395x; 2.8395x over previous
//
#include <hip/hip_runtime.h>
#include <hip/hip_fp16.h>

// Problem constants: B=16, N=128, H=128, BD=64, P=256
using f16x4 = __attribute__((ext_vector_type(4))) _Float16;
using f16x8 = __attribute__((ext_vector_type(8))) _Float16;
using f32x4 = __attribute__((ext_vector_type(4))) float;

__device__ __forceinline__ f16x4 ld_f16x4(const void* p) {
    return *reinterpret_cast<const f16x4*>(p);
}
__device__ __forceinline__ f16x8 ld_f16x8(const void* p) {
    return *reinterpret_cast<const f16x8*>(p);
}

// ---------------------------------------------------------------------------
// k-slot convention (consistent across BOTH MFMA operands => contraction is
// exact for any bijection): for K=32 f16 MFMA, lane group lk (lane>>4),
// register element e (0..7) holds k-slot (lk, e).
//  GEMM1 labeling: k = s32*32 + lk*8 + e          (plain, W2bt = plain transpose)
//  GEMM2 labeling: k = ks*32 + sigma(lk,e), sigma = (e>>2)*16 + 4*lk + (e&3)
//   (matches GEMM1's C/D quad packing of u, so u needs NO shuffles).
//
// Prep kernel A: W2bt[p][k] = W2[128+k][p] (f16 plain transpose, 64/row).
//  W3 -> W3s: [ks][row p'][4 slots x 8 f16]; slot s at row holds k-group
//  g = s ^ ((row>>1)&3) (read-side bank swizzle folded in), element e ->
//  k = ks*32 + sigma(g,e).
// ---------------------------------------------------------------------------
__global__ void sp_wconv(const float* __restrict__ W2, const float* __restrict__ W3,
                         _Float16* __restrict__ W2bt, _Float16* __restrict__ W3s) {
    int t = blockIdx.x * 256 + threadIdx.x;   // grid covers 65536
    if (t < 16384) {
        int p = t >> 6, k = t & 63;
        W2bt[t] = (_Float16)W2[(128 + k) * 256 + p];
    }
    {
        int ks = t >> 13, rem = t & 8191;
        int row = rem >> 5, inner = rem & 31;
        int slot = inner >> 3, e = inner & 7;
        int g = slot ^ ((row >> 1) & 3);
        int k = ks * 32 + ((e & 4) << 2) + (g << 2) + (e & 3);
        W3s[t] = (_Float16)W3[k * 256 + row];
    }
}

// ---------------------------------------------------------------------------
// Prep kernel B: hp16[b*128+j][p] = hid[b,j,:] @ W2[0:128,p] + b2[p]  (f16)
// ---------------------------------------------------------------------------
__global__ void sp_hpart(const float* __restrict__ hs, const float* __restrict__ W2,
                         const float* __restrict__ b2, _Float16* __restrict__ hp16) {
    __shared__ float sh[8 * 128];
    int rb = blockIdx.x * 8;
    int tid = threadIdx.x;
    for (int t = tid; t < 1024; t += 256) sh[t] = hs[rb * 128 + t];
    __syncthreads();
    float acc[8];
    float bb = b2[tid];
#pragma unroll
    for (int r = 0; r < 8; ++r) acc[r] = bb;
    for (int k = 0; k < 128; ++k) {
        float w = W2[k * 256 + tid];
#pragma unroll
        for (int r = 0; r < 8; ++r) acc[r] += sh[r * 128 + k] * w;
    }
#pragma unroll
    for (int r = 0; r < 8; ++r) hp16[(rb + r) * 256 + tid] = (_Float16)acc[r];
}

// ---------------------------------------------------------------------------
// Main kernel: one block per (b, ph, i-group of 8) -> grid 512 (2 blocks/CU).
// 4 waves; wave wj owns j in [32wj, 32wj+32).
//  Stage W3 half (64KB) to LDS ONCE (1 barrier). Then 8 i-iterations with
//  ZERO barriers (sW3 read-only; each wave writes its private sPoolH slice).
//  SLIM registers (r10 spilled from cached invariants + full-unroll hoist):
//  no cached W1/b1 frags (reloaded per i, L1-hot), unroll caps on MFMA loops.
//  Per i: enc -> GEMM1 (K=32, transposed) -> u in regs -> GEMM2 (K=32) from
//  resident LDS -> per-wave masked max -> sPoolH.
//  Block end: 1 barrier, cross-wave max + b3 -> pooled rows (d_out).
// LDS: 64KB W3 + 8KB pool = 72KB -> 2 blocks/CU. Peak regs ~140 -> (256,2).
// ---------------------------------------------------------------------------
__global__ __launch_bounds__(256, 2) void sp_main(
    const float* __restrict__ pos, const float* __restrict__ W1,
    const float* __restrict__ b1, const float* __restrict__ b3,
    const _Float16* __restrict__ hp16, const _Float16* __restrict__ W2bt,
    const _Float16* __restrict__ W3s, float* __restrict__ pool) {
    __shared__ __align__(16) char sW3[8][8192];    // [ks][row'-local 128][64B]
    __shared__ _Float16 sPoolH[4][8][128];         // [wj][ii][p'-local]

    const int bid = blockIdx.x;
    const int ig = bid & 15, ph = (bid >> 4) & 1, b = bid >> 5;
    const int tid = threadIdx.x;
    const int wj = tid >> 6, lane = tid & 63;
    const int l15 = lane & 15, lk = lane >> 4;

    // --- stage W3 half (64KB) once; linear conflict-free writes ------------
    {
        const uint4* W3v = (const uint4*)W3s + ph * 512;
        uint4* dst = (uint4*)sW3;
#pragma unroll
        for (int c = 0; c < 16; ++c) {
            dst[c * 256 + tid] = W3v[c * 256 + tid + (c >> 1) * 512];
        }
    }

    // minimal persistent state: j-positions (4 regs) + hp base pointer
    float pjx[2], pjy[2];
#pragma unroll
    for (int jt = 0; jt < 2; ++jt) {
        int j = wj * 32 + jt * 16 + l15;
        pjx[jt] = pos[(b * 128 + j) * 2 + 0];
        pjy[jt] = pos[(b * 128 + j) * 2 + 1];
    }
    const _Float16* hpb = hp16 + (b * 128 + wj * 32 + l15) * 256 + lk * 4;
    const int slot = lk ^ ((l15 >> 1) & 3);   // read-side bank swizzle

    __syncthreads();   // sW3 ready

    // ======================= barrier-free i-loop ===========================
#pragma unroll 1
    for (int ii = 0; ii < 8; ++ii) {
        const int i = ig * 8 + ii;
        const float pix = pos[(b * 128 + i) * 2 + 0];
        const float piy = pos[(b * 128 + i) * 2 + 1];

        // --- enc as K=32 B-fragments: k = s32*32 + lk*8 + e ----------------
        // W1/b1 fragments reloaded each i (L1-hot) to keep live regs low.
        f16x8 benc[2][2];
#pragma unroll
        for (int s32 = 0; s32 < 2; ++s32) {
            int k0 = s32 * 32 + lk * 8;
            f32x4 x0 = *(const f32x4*)(W1 + k0), x1 = *(const f32x4*)(W1 + k0 + 4);
            f32x4 y0 = *(const f32x4*)(W1 + 64 + k0), y1 = *(const f32x4*)(W1 + 64 + k0 + 4);
            f32x4 c0 = *(const f32x4*)(b1 + k0), c1 = *(const f32x4*)(b1 + k0 + 4);
#pragma unroll
            for (int jt = 0; jt < 2; ++jt) {
                float rx = pjx[jt] - pix, ry = pjy[jt] - piy;
                f16x8 v;
#pragma unroll
                for (int e = 0; e < 4; ++e) {
                    float t0 = fmaf(rx, x0[e], fmaf(ry, y0[e], c0[e]));
                    float t1 = fmaf(rx, x1[e], fmaf(ry, y1[e], c1[e]));
                    v[e]     = (_Float16)(t0 > 0.f ? t0 : 0.f);
                    v[e + 4] = (_Float16)(t1 > 0.f ? t1 : 0.f);
                }
                benc[jt][s32] = v;
            }
        }

        // --- GEMM1 (transposed, K=32) + pack u = GEMM2 A-frags -------------
        // D: p = pt*16 + 4lk + r, j = wj*32 + jt*16 + l15
        // unroll 4: limits aw/h load hoisting (r10's full unroll -> spill)
        f16x8 u[2][8];
#pragma unroll 4
        for (int pt = 0; pt < 16; ++pt) {
            f32x4 a0 = (f32x4){0.f, 0.f, 0.f, 0.f};
            f32x4 a1 = (f32x4){0.f, 0.f, 0.f, 0.f};
#pragma unroll
            for (int s32 = 0; s32 < 2; ++s32) {
                f16x8 aw = ld_f16x8(W2bt + (pt * 16 + l15) * 64 + s32 * 32 + lk * 8);
                a0 = __builtin_amdgcn_mfma_f32_16x16x32_f16(aw, benc[0][s32], a0, 0, 0, 0);
                a1 = __builtin_amdgcn_mfma_f32_16x16x32_f16(aw, benc[1][s32], a1, 0, 0, 0);
            }
            f16x4 h0 = ld_f16x4(hpb + pt * 16);
            f16x4 h1 = ld_f16x4(hpb + 16 * 256 + pt * 16);
            const int ks = pt >> 1, half = (pt & 1) * 4;
#pragma unroll
            for (int r = 0; r < 4; ++r) {
                float t0 = a0[r] + (float)h0[r];
                float t1 = a1[r] + (float)h1[r];
                u[0][ks][half + r] = (_Float16)(t0 > 0.f ? t0 : 0.f);
                u[1][ks][half + r] = (_Float16)(t1 > 0.f ? t1 : 0.f);
            }
        }

        // --- GEMM2 (K=32) from resident LDS, no barriers --------------------
        f32x4 eacc[2][8];
#pragma unroll
        for (int jt = 0; jt < 2; ++jt)
#pragma unroll
            for (int pt = 0; pt < 8; ++pt) eacc[jt][pt] = (f32x4){0.f, 0.f, 0.f, 0.f};

#pragma unroll 2
        for (int ks = 0; ks < 8; ++ks) {
#pragma unroll
            for (int pt = 0; pt < 8; ++pt) {
                f16x8 bf = ld_f16x8(sW3[ks] + (pt * 16 + l15) * 64 + slot * 16);
                eacc[0][pt] = __builtin_amdgcn_mfma_f32_16x16x32_f16(u[0][ks], bf, eacc[0][pt], 0, 0, 0);
                eacc[1][pt] = __builtin_amdgcn_mfma_f32_16x16x32_f16(u[1][ks], bf, eacc[1][pt], 0, 0, 0);
            }
        }

        // --- masked max over this wave's 32 j -> private sPoolH slice ------
        // eacc: row j = wj*32 + jt*16 + 4lk + r, col p' = ph*128 + pt*16 + l15
#pragma unroll
        for (int pt = 0; pt < 8; ++pt) {
            float m = -INFINITY;
#pragma unroll
            for (int jt = 0; jt < 2; ++jt) {
#pragma unroll
                for (int r = 0; r < 4; ++r) {
                    int row = wj * 32 + jt * 16 + lk * 4 + r;
                    float v = eacc[jt][pt][r];
                    if (row != i) m = fmaxf(m, v);
                }
            }
            m = fmaxf(m, __shfl_xor(m, 16));
            m = fmaxf(m, __shfl_xor(m, 32));
            if (lane < 16) sPoolH[wj][ii][pt * 16 + l15] = (_Float16)m;
        }
    }
    __syncthreads();   // all waves' sPoolH complete

    // --- cross-wave max + b3 -> pooled rows (d_out, write-only) ------------
#pragma unroll
    for (int q = 0; q < 4; ++q) {
        int idx = q * 256 + tid;           // 0..1023 = 8 ii x 128 p'-local
        int ii = idx >> 7, t = idx & 127;
        float v = fmaxf(fmaxf((float)sPoolH[0][ii][t], (float)sPoolH[1][ii][t]),
                        fmaxf((float)sPoolH[2][ii][t], (float)sPoolH[3][ii][t]));
        int p = ph * 128 + t;
        pool[(b * 128 + ig * 8 + ii) * 256 + p] = v + b3[p];
    }
}

// ---------------------------------------------------------------------------
// Final: io = io @ Wout + bout, IN PLACE on d_out (8 rows per block; rows
// staged to LDS behind a barrier before any write -> in-place safe).
// ---------------------------------------------------------------------------
__global__ void sp_out(const float* __restrict__ Wout, const float* __restrict__ bout,
                       float* __restrict__ io) {
    __shared__ float sp[8 * 256];
    int rb = blockIdx.x * 8;
    int tid = threadIdx.x;
    for (int t = tid; t < 2048; t += 256) sp[t] = io[rb * 256 + t];
    __syncthreads();
    float acc[8];
    float bb = bout[tid];
#pragma unroll
    for (int r = 0; r < 8; ++r) acc[r] = bb;
    for (int k = 0; k < 256; ++k) {
        float w = Wout[k * 256 + tid];
#pragma unroll
        for (int r = 0; r < 8; ++r) acc[r] += sp[r * 256 + k] * w;
    }
#pragma unroll
    for (int r = 0; r < 8; ++r) io[(rb + r) * 256 + tid] = acc[r];
}

extern "C" void kernel_launch(void* const* d_in, const int* in_sizes, int n_in,
                              void* d_out, int out_size, void* d_ws, size_t ws_size,
                              hipStream_t stream) {
    const float* hs   = (const float*)d_in[0];
    const float* pos  = (const float*)d_in[1];
    const float* W1   = (const float*)d_in[2];
    const float* b1   = (const float*)d_in[3];
    const float* W2   = (const float*)d_in[4];
    const float* b2   = (const float*)d_in[5];
    const float* W3   = (const float*)d_in[6];
    const float* b3   = (const float*)d_in[7];
    const float* Wout = (const float*)d_in[8];
    const float* bout = (const float*)d_in[9];
    float* out = (float*)d_out;

    // ws layout: hp16 1MB | W2bt 32KB | W3s 128KB  (~1.2MB total)
    _Float16* hp16 = (_Float16*)d_ws;
    _Float16* W2bt = (_Float16*)((char*)d_ws + (1 << 20));
    _Float16* W3s  = (_Float16*)((char*)d_ws + (1 << 20) + 32768);

    sp_wconv<<<256, 256, 0, stream>>>(W2, W3, W2bt, W3s);
    sp_hpart<<<256, 256, 0, stream>>>(hs, W2, b2, hp16);
    sp_main<<<512, 256, 0, stream>>>(pos, W1, b1, b3, hp16, W2bt, W3s, out);
    sp_out<<<256, 256, 0, stream>>>(Wout, bout, out);
}

// Round 12
// 151.229 us; speedup vs baseline: 4.1610x; 1.4654x over previous
//
#include <hip/hip_runtime.h>
#include <hip/hip_fp16.h>

// Problem constants: B=16, N=128, H=128, BD=64, P=256
using f16x4 = __attribute__((ext_vector_type(4))) _Float16;
using f16x8 = __attribute__((ext_vector_type(8))) _Float16;
using f32x4 = __attribute__((ext_vector_type(4))) float;

__device__ __forceinline__ f16x4 ld_f16x4(const void* p) {
    return *reinterpret_cast<const f16x4*>(p);
}
__device__ __forceinline__ f16x8 ld_f16x8(const void* p) {
    return *reinterpret_cast<const f16x8*>(p);
}

// ---------------------------------------------------------------------------
// k-slot convention (consistent across BOTH MFMA operands => contraction is
// exact for any bijection): for K=32 f16 MFMA, lane group lk (lane>>4),
// register element e (0..7) holds k-slot (lk, e).
//  GEMM1 labeling: k = s32*32 + lk*8 + e          (plain, W2bt = plain transpose)
//  GEMM2 labeling: k = ks*32 + sigma(lk,e), sigma = (e>>2)*16 + 4*lk + (e&3)
//   (matches GEMM1's C/D quad packing of u, so u needs NO shuffles).
//
// Prep kernel A: W2bt[p][k] = W2[128+k][p] (f16 plain transpose, 64/row).
//  W3 -> W3s: [ks][row p'][4 slots x 8 f16]; slot s at row holds k-group
//  g = s ^ ((row>>1)&3) (read-side bank swizzle folded in), element e ->
//  k = ks*32 + sigma(g,e).
// ---------------------------------------------------------------------------
__global__ void sp_wconv(const float* __restrict__ W2, const float* __restrict__ W3,
                         _Float16* __restrict__ W2bt, _Float16* __restrict__ W3s) {
    int t = blockIdx.x * 256 + threadIdx.x;   // grid covers 65536
    if (t < 16384) {
        int p = t >> 6, k = t & 63;
        W2bt[t] = (_Float16)W2[(128 + k) * 256 + p];
    }
    {
        int ks = t >> 13, rem = t & 8191;
        int row = rem >> 5, inner = rem & 31;
        int slot = inner >> 3, e = inner & 7;
        int g = slot ^ ((row >> 1) & 3);
        int k = ks * 32 + ((e & 4) << 2) + (g << 2) + (e & 3);
        W3s[t] = (_Float16)W3[k * 256 + row];
    }
}

// ---------------------------------------------------------------------------
// Prep kernel B: hp16[b*128+j][p] = hid[b,j,:] @ W2[0:128,p] + b2[p]  (f16)
// ---------------------------------------------------------------------------
__global__ void sp_hpart(const float* __restrict__ hs, const float* __restrict__ W2,
                         const float* __restrict__ b2, _Float16* __restrict__ hp16) {
    __shared__ float sh[8 * 128];
    int rb = blockIdx.x * 8;
    int tid = threadIdx.x;
    for (int t = tid; t < 1024; t += 256) sh[t] = hs[rb * 128 + t];
    __syncthreads();
    float acc[8];
    float bb = b2[tid];
#pragma unroll
    for (int r = 0; r < 8; ++r) acc[r] = bb;
    for (int k = 0; k < 128; ++k) {
        float w = W2[k * 256 + tid];
#pragma unroll
        for (int r = 0; r < 8; ++r) acc[r] += sh[r * 128 + k] * w;
    }
#pragma unroll
    for (int r = 0; r < 8; ++r) hp16[(rb + r) * 256 + tid] = (_Float16)acc[r];
}

// ---------------------------------------------------------------------------
// Main kernel: one block per (b, ph, i-group of 8) -> grid 512 (2 blocks/CU).
// 4 waves; wave wj owns j in [32wj, 32wj+32).
//  Stage W3 half (64KB) to LDS ONCE (1 barrier). Then 8 i-iterations with
//  ZERO barriers (sW3 read-only; each wave writes its private sPoolH slice).
//  Register discipline (r10/r11 lessons):
//   - FULL unrolls on MFMA loops => all array indices static (rule #20,
//     no scratch);
//   - opaque pointer passthroughs (asm "+v") at the top of each i-iteration
//     block LICM from hoisting the i-invariant W2bt/W1/b1/hp loads into
//     ~170 persistent registers (r10's spill). Loads stay per-i, L1-hot.
//  Per i: enc -> GEMM1 (K=32, transposed) -> u in regs -> GEMM2 (K=32) from
//  resident LDS -> per-wave masked max -> sPoolH.
//  Block end: 1 barrier, cross-wave max + b3 -> pooled rows (d_out).
// LDS: 64KB W3 + 8KB pool = 72KB -> 2 blocks/CU. Peak live ~150 -> (256,2).
// ---------------------------------------------------------------------------
__global__ __launch_bounds__(256, 2) void sp_main(
    const float* __restrict__ pos, const float* __restrict__ W1,
    const float* __restrict__ b1, const float* __restrict__ b3,
    const _Float16* __restrict__ hp16, const _Float16* __restrict__ W2bt,
    const _Float16* __restrict__ W3s, float* __restrict__ pool) {
    __shared__ __align__(16) char sW3[8][8192];    // [ks][row'-local 128][64B]
    __shared__ _Float16 sPoolH[4][8][128];         // [wj][ii][p'-local]

    const int bid = blockIdx.x;
    const int ig = bid & 15, ph = (bid >> 4) & 1, b = bid >> 5;
    const int tid = threadIdx.x;
    const int wj = tid >> 6, lane = tid & 63;
    const int l15 = lane & 15, lk = lane >> 4;

    // --- stage W3 half (64KB) once; linear conflict-free writes ------------
    {
        const uint4* W3v = (const uint4*)W3s + ph * 512;
        uint4* dst = (uint4*)sW3;
#pragma unroll
        for (int c = 0; c < 16; ++c) {
            dst[c * 256 + tid] = W3v[c * 256 + tid + (c >> 1) * 512];
        }
    }

    // minimal persistent state: j-positions (4 regs) + base pointers
    float pjx[2], pjy[2];
#pragma unroll
    for (int jt = 0; jt < 2; ++jt) {
        int j = wj * 32 + jt * 16 + l15;
        pjx[jt] = pos[(b * 128 + j) * 2 + 0];
        pjy[jt] = pos[(b * 128 + j) * 2 + 1];
    }
    const _Float16* hpb = hp16 + (b * 128 + wj * 32 + l15) * 256 + lk * 4;
    const int slot = lk ^ ((l15 >> 1) & 3);   // read-side bank swizzle

    __syncthreads();   // sW3 ready

    // ======================= barrier-free i-loop ===========================
#pragma unroll 1
    for (int ii = 0; ii < 8; ++ii) {
        const int i = ig * 8 + ii;
        const float pix = pos[(b * 128 + i) * 2 + 0];
        const float piy = pos[(b * 128 + i) * 2 + 1];

        // Opaque passthroughs: compiler must assume these change per
        // iteration -> blocks LICM hoisting of all loads derived from them.
        const float* W1p = W1;
        const float* b1p = b1;
        const _Float16* w2p = W2bt;
        const _Float16* hpp = hpb;
        asm volatile("" : "+v"(W1p), "+v"(b1p), "+v"(w2p), "+v"(hpp));

        // --- enc as K=32 B-fragments: k = s32*32 + lk*8 + e ----------------
        f16x8 benc[2][2];
#pragma unroll
        for (int s32 = 0; s32 < 2; ++s32) {
            int k0 = s32 * 32 + lk * 8;
            f32x4 x0 = *(const f32x4*)(W1p + k0), x1 = *(const f32x4*)(W1p + k0 + 4);
            f32x4 y0 = *(const f32x4*)(W1p + 64 + k0), y1 = *(const f32x4*)(W1p + 64 + k0 + 4);
            f32x4 c0 = *(const f32x4*)(b1p + k0), c1 = *(const f32x4*)(b1p + k0 + 4);
#pragma unroll
            for (int jt = 0; jt < 2; ++jt) {
                float rx = pjx[jt] - pix, ry = pjy[jt] - piy;
                f16x8 v;
#pragma unroll
                for (int e = 0; e < 4; ++e) {
                    float t0 = fmaf(rx, x0[e], fmaf(ry, y0[e], c0[e]));
                    float t1 = fmaf(rx, x1[e], fmaf(ry, y1[e], c1[e]));
                    v[e]     = (_Float16)(t0 > 0.f ? t0 : 0.f);
                    v[e + 4] = (_Float16)(t1 > 0.f ? t1 : 0.f);
                }
                benc[jt][s32] = v;
            }
        }

        // --- GEMM1 (transposed, K=32) + pack u = GEMM2 A-frags -------------
        // D: p = pt*16 + 4lk + r, j = wj*32 + jt*16 + l15.  FULL unroll:
        // all u indices compile-time constant (no scratch).
        f16x8 u[2][8];
#pragma unroll
        for (int pt = 0; pt < 16; ++pt) {
            f32x4 a0 = (f32x4){0.f, 0.f, 0.f, 0.f};
            f32x4 a1 = (f32x4){0.f, 0.f, 0.f, 0.f};
#pragma unroll
            for (int s32 = 0; s32 < 2; ++s32) {
                f16x8 aw = ld_f16x8(w2p + (pt * 16 + l15) * 64 + s32 * 32 + lk * 8);
                a0 = __builtin_amdgcn_mfma_f32_16x16x32_f16(aw, benc[0][s32], a0, 0, 0, 0);
                a1 = __builtin_amdgcn_mfma_f32_16x16x32_f16(aw, benc[1][s32], a1, 0, 0, 0);
            }
            f16x4 h0 = ld_f16x4(hpp + pt * 16);
            f16x4 h1 = ld_f16x4(hpp + 16 * 256 + pt * 16);
            const int ks = pt >> 1, half = (pt & 1) * 4;
#pragma unroll
            for (int r = 0; r < 4; ++r) {
                float t0 = a0[r] + (float)h0[r];
                float t1 = a1[r] + (float)h1[r];
                u[0][ks][half + r] = (_Float16)(t0 > 0.f ? t0 : 0.f);
                u[1][ks][half + r] = (_Float16)(t1 > 0.f ? t1 : 0.f);
            }
        }

        // --- GEMM2 (K=32) from resident LDS, no barriers --------------------
        f32x4 eacc[2][8];
#pragma unroll
        for (int jt = 0; jt < 2; ++jt)
#pragma unroll
            for (int pt = 0; pt < 8; ++pt) eacc[jt][pt] = (f32x4){0.f, 0.f, 0.f, 0.f};

#pragma unroll
        for (int ks = 0; ks < 8; ++ks) {
#pragma unroll
            for (int pt = 0; pt < 8; ++pt) {
                f16x8 bf = ld_f16x8(sW3[ks] + (pt * 16 + l15) * 64 + slot * 16);
                eacc[0][pt] = __builtin_amdgcn_mfma_f32_16x16x32_f16(u[0][ks], bf, eacc[0][pt], 0, 0, 0);
                eacc[1][pt] = __builtin_amdgcn_mfma_f32_16x16x32_f16(u[1][ks], bf, eacc[1][pt], 0, 0, 0);
            }
        }

        // --- masked max over this wave's 32 j -> private sPoolH slice ------
        // eacc: row j = wj*32 + jt*16 + 4lk + r, col p' = ph*128 + pt*16 + l15
#pragma unroll
        for (int pt = 0; pt < 8; ++pt) {
            float m = -INFINITY;
#pragma unroll
            for (int jt = 0; jt < 2; ++jt) {
#pragma unroll
                for (int r = 0; r < 4; ++r) {
                    int row = wj * 32 + jt * 16 + lk * 4 + r;
                    float v = eacc[jt][pt][r];
                    if (row != i) m = fmaxf(m, v);
                }
            }
            m = fmaxf(m, __shfl_xor(m, 16));
            m = fmaxf(m, __shfl_xor(m, 32));
            if (lane < 16) sPoolH[wj][ii][pt * 16 + l15] = (_Float16)m;
        }
    }
    __syncthreads();   // all waves' sPoolH complete

    // --- cross-wave max + b3 -> pooled rows (d_out, write-only) ------------
#pragma unroll
    for (int q = 0; q < 4; ++q) {
        int idx = q * 256 + tid;           // 0..1023 = 8 ii x 128 p'-local
        int ii = idx >> 7, t = idx & 127;
        float v = fmaxf(fmaxf((float)sPoolH[0][ii][t], (float)sPoolH[1][ii][t]),
                        fmaxf((float)sPoolH[2][ii][t], (float)sPoolH[3][ii][t]));
        int p = ph * 128 + t;
        pool[(b * 128 + ig * 8 + ii) * 256 + p] = v + b3[p];
    }
}

// ---------------------------------------------------------------------------
// Final: io = io @ Wout + bout, IN PLACE on d_out (8 rows per block; rows
// staged to LDS behind a barrier before any write -> in-place safe).
// ---------------------------------------------------------------------------
__global__ void sp_out(const float* __restrict__ Wout, const float* __restrict__ bout,
                       float* __restrict__ io) {
    __shared__ float sp[8 * 256];
    int rb = blockIdx.x * 8;
    int tid = threadIdx.x;
    for (int t = tid; t < 2048; t += 256) sp[t] = io[rb * 256 + t];
    __syncthreads();
    float acc[8];
    float bb = bout[tid];
#pragma unroll
    for (int r = 0; r < 8; ++r) acc[r] = bb;
    for (int k = 0; k < 256; ++k) {
        float w = Wout[k * 256 + tid];
#pragma unroll
        for (int r = 0; r < 8; ++r) acc[r] += sp[r * 256 + k] * w;
    }
#pragma unroll
    for (int r = 0; r < 8; ++r) io[(rb + r) * 256 + tid] = acc[r];
}

extern "C" void kernel_launch(void* const* d_in, const int* in_sizes, int n_in,
                              void* d_out, int out_size, void* d_ws, size_t ws_size,
                              hipStream_t stream) {
    const float* hs   = (const float*)d_in[0];
    const float* pos  = (const float*)d_in[1];
    const float* W1   = (const float*)d_in[2];
    const float* b1   = (const float*)d_in[3];
    const float* W2   = (const float*)d_in[4];
    const float* b2   = (const float*)d_in[5];
    const float* W3   = (const float*)d_in[6];
    const float* b3   = (const float*)d_in[7];
    const float* Wout = (const float*)d_in[8];
    const float* bout = (const float*)d_in[9];
    float* out = (float*)d_out;

    // ws layout: hp16 1MB | W2bt 32KB | W3s 128KB  (~1.2MB total)
    _Float16* hp16 = (_Float16*)d_ws;
    _Float16* W2bt = (_Float16*)((char*)d_ws + (1 << 20));
    _Float16* W3s  = (_Float16*)((char*)d_ws + (1 << 20) + 32768);

    sp_wconv<<<256, 256, 0, stream>>>(W2, W3, W2bt, W3s);
    sp_hpart<<<256, 256, 0, stream>>>(hs, W2, b2, hp16);
    sp_main<<<512, 256, 0, stream>>>(pos, W1, b1, b3, hp16, W2bt, W3s, out);
    sp_out<<<256, 256, 0, stream>>>(Wout, bout, out);
}